// Round 5
// baseline (505.229 us; speedup 1.0000x reference)
//
#include <hip/hip_runtime.h>
#include <cstdint>
#include <cstddef>

// ---------- types & helpers ----------
typedef __attribute__((ext_vector_type(8))) short bfr8;   // 8 bf16 = 4 VGPRs
typedef __attribute__((ext_vector_type(4))) float acc4;   // MFMA accumulator

__device__ __forceinline__ float bf2f(short s) {
  return __uint_as_float(((unsigned)(unsigned short)s) << 16);
}
__device__ __forceinline__ short f2bf(float f) {
  unsigned u = __float_as_uint(f);
  u += 0x7fffu + ((u >> 16) & 1u);   // round-to-nearest-even
  return (short)(u >> 16);
}
// fast tanh-approx GELU: tanh via v_exp_f32, clamped to avoid inf/inf
__device__ __forceinline__ float gelu_f(float x) {
  float z = 0.7978845608028654f * (x + 0.044715f * x * x * x);
  z = fminf(fmaxf(z, -12.f), 12.f);
  float e = __expf(2.f * z);
  float th = (e - 1.f) / (e + 1.f);
  return 0.5f * x * (1.f + th);
}
// async global->LDS, 16B per lane; lds dest = wave-uniform base + lane*16
__device__ __forceinline__ void load_lds16(const short* g, short* l) {
  __builtin_amdgcn_global_load_lds(
      (const __attribute__((address_space(1))) void*)g,
      (__attribute__((address_space(3))) void*)l, 16, 0, 0);
}

// Problem constants
#define BB 2
#define SS 4096
#define DD 768
#define HH 12
#define BLKSZ 64
#define NBLK 64
#define HDIM 64

// ---------- merged weight prep: 6 transposes (fp32[K][N] -> bf16[N][K]) + bias concat ----------
__global__ __launch_bounds__(256) void prep_weights(
    const float* __restrict__ wq, const float* __restrict__ wk,
    const float* __restrict__ wv, const float* __restrict__ wo,
    const float* __restrict__ w1, const float* __restrict__ w2,
    const float* __restrict__ bq, const float* __restrict__ bk,
    const float* __restrict__ bv, float* __restrict__ bqkv,
    short* __restrict__ wqT, short* __restrict__ wkT, short* __restrict__ wvT,
    short* __restrict__ woT, short* __restrict__ w1T, short* __restrict__ w2T) {
  int id = blockIdx.x;
  if (id >= 6912) {  // bias concat, 9 blocks x 256 = 2304
    int t = (id - 6912) * 256 + threadIdx.x;
    bqkv[t] = (t < 768) ? bq[t] : (t < 1536) ? bk[t - 768] : bv[t - 1536];
    return;
  }
  const float* src; short* dst; int K, N, n0, k0;
  if (id < 2304) {
    int seg = id / 576, local = id % 576;
    K = 768; N = 768;
    n0 = (local % 24) * 32; k0 = (local / 24) * 32;
    src = seg == 0 ? wq : seg == 1 ? wk : seg == 2 ? wv : wo;
    dst = seg == 0 ? wqT : seg == 1 ? wkT : seg == 2 ? wvT : woT;
  } else if (id < 4608) {
    int local = id - 2304;
    K = 768; N = 3072;
    n0 = (local % 96) * 32; k0 = (local / 96) * 32;
    src = w1; dst = w1T;
  } else {
    int local = id - 4608;
    K = 3072; N = 768;
    n0 = (local % 24) * 32; k0 = (local / 24) * 32;
    src = w2; dst = w2T;
  }
  __shared__ float tile[32][33];
  int tx = threadIdx.x & 31, ty = threadIdx.x >> 5;  // ty in 0..7
#pragma unroll
  for (int i = 0; i < 4; i++) {
    int kk = ty + i * 8;
    tile[kk][tx] = src[(size_t)(k0 + kk) * N + n0 + tx];
  }
  __syncthreads();
#pragma unroll
  for (int i = 0; i < 4; i++) {
    int nn = ty + i * 8;
    dst[(size_t)(n0 + nn) * K + k0 + tx] = f2bf(tile[tx][nn]);
  }
}

// ---------- transpose bf16 [B][S][D] -> [B][D][S] ----------
__global__ __launch_bounds__(256) void transpose_bf16(
    const short* __restrict__ src, short* __restrict__ dst) {
  __shared__ short tile[32][33];
  int b = blockIdx.z;
  int s0 = blockIdx.x * 32, d0 = blockIdx.y * 32;
  int tx = threadIdx.x & 31, ty = threadIdx.x >> 5;  // 0..7
#pragma unroll
  for (int i = 0; i < 4; i++) {
    int ss = ty + i * 8;
    tile[ss][tx] = src[((size_t)b * SS + s0 + ss) * DD + d0 + tx];
  }
  __syncthreads();
#pragma unroll
  for (int i = 0; i < 4; i++) {
    int dd = ty + i * 8;
    dst[((size_t)b * DD + d0 + dd) * SS + s0 + tx] = tile[tx][dd];
  }
}

// ---------- LayerNorm: strided fp32 in -> contiguous bf16 out [rows][768] ----------
__global__ __launch_bounds__(256) void ln_kernel(
    const float* __restrict__ in, int stride, int off,
    const float* __restrict__ gam, const float* __restrict__ bet,
    short* __restrict__ out) {
  int row = blockIdx.x;
  int t = threadIdx.x;
  const float* base = in + (size_t)row * 768 * stride + off;
  float vals[3], s = 0.f, s2 = 0.f;
#pragma unroll
  for (int i = 0; i < 3; i++) {
    int d = t + 256 * i;
    float v = base[(size_t)d * stride];
    vals[i] = v; s += v; s2 += v * v;
  }
#pragma unroll
  for (int o = 32; o; o >>= 1) { s += __shfl_down(s, o); s2 += __shfl_down(s2, o); }
  __shared__ float red[8];
  int lane = t & 63, w = t >> 6;
  if (lane == 0) { red[w] = s; red[4 + w] = s2; }
  __syncthreads();
  s = red[0] + red[1] + red[2] + red[3];
  s2 = red[4] + red[5] + red[6] + red[7];
  float mean = s * (1.f / 768.f);
  float var = s2 * (1.f / 768.f) - mean * mean;
  float rstd = rsqrtf(var + 1e-6f);
#pragma unroll
  for (int i = 0; i < 3; i++) {
    int d = t + 256 * i;
    out[(size_t)row * 768 + d] = f2bf((vals[i] - mean) * rstd * gam[d] + bet[d]);
  }
}

// ---------- bf16 MFMA GEMM, global_load_lds staging, templated tile ----------
// Tile: BM x BN (64/128 each). 4 waves in 2x2; wave owns (BM/2) x (BN/2).
// C[M][N] = A[M][K] @ BT[N][K]^T + bias, epilogues:
// EPI 1: y2 = acc + bias + x[idx*2+0]  -> outf[idx*2+1]   (N=768)
// EPI 2: out bf16 = gelu(acc + bias)
// EPI 3: y1 = acc + bias + x[idx*2+1]  -> outf[idx*2+0]   (N=768)
// EPI 4: fused QKV: col/768 selects dest buffer (stride ACT), out bf16 row-major 768
template <int BM, int BN, int EPI>
__global__ __launch_bounds__(256) void gemm_lds(
    const short* __restrict__ A, const short* __restrict__ BT,
    const float* __restrict__ bias, const float* __restrict__ xres,
    void* __restrict__ outp, int M, int N, int K) {
  __shared__ alignas(16) short As[BM * 64];   // unpadded: required by global_load_lds
  __shared__ alignas(16) short Bs[BN * 64];
  constexpr int TI = BM / 32;  // acc i-tiles per wave == A-staging issues per wave
  constexpr int TJ = BN / 32;
  int m0 = blockIdx.y * BM, n0 = blockIdx.x * BN;
  int t = threadIdx.x;
  int lane = t & 63, wave = t >> 6;
  int wm = (wave >> 1) * (BM / 2), wn = (wave & 1) * (BN / 2);
  int quad = lane >> 4, lc = lane & 15;
  acc4 acc[TI][TJ];
#pragma unroll
  for (int i = 0; i < TI; i++)
#pragma unroll
    for (int j = 0; j < TJ; j++) acc[i][j] = (acc4){0.f, 0.f, 0.f, 0.f};

  // staging geometry: wave covers flat shorts [wave*(BM*16)...]; issue advances 512 (=8 rows)
  int aflat = wave * (BM * 16) + lane * 8;
  const short* Ag = A + (size_t)(m0 + (aflat >> 6)) * K + (aflat & 63);
  int bflat = wave * (BN * 16) + lane * 8;
  const short* Bg = BT + (size_t)(n0 + (bflat >> 6)) * K + (bflat & 63);

  for (int k0 = 0; k0 < K; k0 += 64) {
#pragma unroll
    for (int j = 0; j < TI; j++)
      load_lds16(Ag + k0 + (size_t)(j * 8) * K, &As[wave * (BM * 16) + j * 512]);
#pragma unroll
    for (int j = 0; j < TJ; j++)
      load_lds16(Bg + k0 + (size_t)(j * 8) * K, &Bs[wave * (BN * 16) + j * 512]);
    __syncthreads();
#pragma unroll
    for (int kk = 0; kk < 2; kk++) {
      int kof = kk * 32 + quad * 8;
      bfr8 afr[TI], bfr[TJ];
#pragma unroll
      for (int i = 0; i < TI; i++) afr[i] = *(const bfr8*)&As[(wm + i * 16 + lc) * 64 + kof];
#pragma unroll
      for (int j = 0; j < TJ; j++) bfr[j] = *(const bfr8*)&Bs[(wn + j * 16 + lc) * 64 + kof];
#pragma unroll
      for (int i = 0; i < TI; i++)
#pragma unroll
        for (int j = 0; j < TJ; j++)
          acc[i][j] = __builtin_amdgcn_mfma_f32_16x16x32_bf16(afr[i], bfr[j], acc[i][j], 0, 0, 0);
    }
    __syncthreads();
  }
  // epilogue: C/D layout col=lane&15, row=(lane>>4)*4+reg
#pragma unroll
  for (int i = 0; i < TI; i++) {
#pragma unroll
    for (int j = 0; j < TJ; j++) {
      int col = n0 + wn + j * 16 + lc;
      float bv = bias[col];
#pragma unroll
      for (int r = 0; r < 4; r++) {
        int row = m0 + wm + i * 16 + quad * 4 + r;
        float v = acc[i][j][r] + bv;
        if (EPI == 1) {
          size_t idx = (size_t)row * N + col;
          v += xres[idx * 2];
          ((float*)outp)[idx * 2 + 1] = v;
        } else if (EPI == 2) {
          size_t idx = (size_t)row * N + col;
          ((short*)outp)[idx] = f2bf(gelu_f(v));
        } else if (EPI == 3) {
          size_t idx = (size_t)row * N + col;
          v += xres[idx * 2 + 1];
          ((float*)outp)[idx * 2] = v;
        } else {  // EPI 4: QKV split (N=2304; 16-col group never straddles a 768 boundary)
          int bufidx = col / 768;
          int colm = col - bufidx * 768;
          ((short*)outp)[(size_t)bufidx * 6291456 + (size_t)row * 768 + colm] = f2bf(v);
        }
      }
    }
  }
}

// ---------- MFMA attention core ----------
__device__ __forceinline__ void attn_core(
    const short* __restrict__ qrow0, const short* __restrict__ kbase,
    const short* __restrict__ vt_h, const int* kblist, int nch, int t,
    short (*QPs)[72], short (*Ks)[72], short (*Vts)[72],
    float* m, float* l, acc4* O) {
  int lane = t & 63, w = t >> 6, quad = lane >> 4, lc = lane & 15;
  // stage Q
#pragma unroll
  for (int c = t; c < 512; c += 256) {
    int r = c >> 3, dc = c & 7;
    *(bfr8*)&QPs[r][dc * 8] = *(const bfr8*)&qrow0[(size_t)r * DD + dc * 8];
  }
  __syncthreads();
  bfr8 aq0 = *(const bfr8*)&QPs[w * 16 + lc][quad * 8];
  bfr8 aq1 = *(const bfr8*)&QPs[w * 16 + lc][32 + quad * 8];
#pragma unroll
  for (int r = 0; r < 4; r++) { m[r] = -1e30f; l[r] = 0.f; }
#pragma unroll
  for (int dt = 0; dt < 4; dt++) O[dt] = (acc4){0.f, 0.f, 0.f, 0.f};

  for (int ch = 0; ch < nch; ch++) {
    int kb = kblist[ch];
    __syncthreads();  // all waves done reading Ks/Vts (and QPs on ch==0)
#pragma unroll
    for (int c = t; c < 512; c += 256) {
      int r = c >> 3, dc = c & 7;
      *(bfr8*)&Ks[r][dc * 8] = *(const bfr8*)&kbase[((size_t)kb * 64 + r) * DD + dc * 8];
      *(bfr8*)&Vts[r][dc * 8] = *(const bfr8*)&vt_h[(size_t)r * SS + kb * 64 + dc * 8];
    }
    __syncthreads();
    acc4 sacc[4];
#pragma unroll
    for (int nt = 0; nt < 4; nt++) {
      bfr8 bk0 = *(const bfr8*)&Ks[nt * 16 + lc][quad * 8];
      bfr8 bk1 = *(const bfr8*)&Ks[nt * 16 + lc][32 + quad * 8];
      acc4 z = (acc4){0.f, 0.f, 0.f, 0.f};
      z = __builtin_amdgcn_mfma_f32_16x16x32_bf16(aq0, bk0, z, 0, 0, 0);
      z = __builtin_amdgcn_mfma_f32_16x16x32_bf16(aq1, bk1, z, 0, 0, 0);
      sacc[nt] = z;
    }
#pragma unroll
    for (int r = 0; r < 4; r++) {
      float sv[4];
#pragma unroll
      for (int nt = 0; nt < 4; nt++) sv[nt] = sacc[nt][r] * 0.125f;
      float cm = fmaxf(fmaxf(sv[0], sv[1]), fmaxf(sv[2], sv[3]));
      cm = fmaxf(cm, __shfl_xor(cm, 1));
      cm = fmaxf(cm, __shfl_xor(cm, 2));
      cm = fmaxf(cm, __shfl_xor(cm, 4));
      cm = fmaxf(cm, __shfl_xor(cm, 8));
      float mn = fmaxf(m[r], cm);
      float al = __expf(m[r] - mn);
      m[r] = mn;
      float ls = 0.f;
#pragma unroll
      for (int nt = 0; nt < 4; nt++) {
        float p = __expf(sv[nt] - mn);
        ls += p;
        QPs[w * 16 + quad * 4 + r][nt * 16 + lc] = f2bf(p);
      }
      ls += __shfl_xor(ls, 1);
      ls += __shfl_xor(ls, 2);
      ls += __shfl_xor(ls, 4);
      ls += __shfl_xor(ls, 8);
      l[r] = l[r] * al + ls;
#pragma unroll
      for (int dt = 0; dt < 4; dt++) O[dt][r] *= al;
    }
    bfr8 ap0 = *(const bfr8*)&QPs[w * 16 + lc][quad * 8];
    bfr8 ap1 = *(const bfr8*)&QPs[w * 16 + lc][32 + quad * 8];
#pragma unroll
    for (int dt = 0; dt < 4; dt++) {
      bfr8 bv0 = *(const bfr8*)&Vts[dt * 16 + lc][quad * 8];
      bfr8 bv1 = *(const bfr8*)&Vts[dt * 16 + lc][32 + quad * 8];
      O[dt] = __builtin_amdgcn_mfma_f32_16x16x32_bf16(ap0, bv0, O[dt], 0, 0, 0);
      O[dt] = __builtin_amdgcn_mfma_f32_16x16x32_bf16(ap1, bv1, O[dt], 0, 0, 0);
    }
  }
}

// middle query blocks: n = 1..62; keys = {0, 63, n-1, n, n+1, r0, r1, r2}
__global__ __launch_bounds__(256) void attn_mid_mfma(
    const short* __restrict__ qbuf, const short* __restrict__ kbuf,
    const short* __restrict__ vtbuf, const int* __restrict__ rand_attn,
    short* __restrict__ ao) {
  int n = 1 + blockIdx.x;  // 1..62
  int h = blockIdx.y, b = blockIdx.z;
  int t = threadIdx.x, lane = t & 63, w = t >> 6, quad = lane >> 4, lc = lane & 15;
  int hoff = h * HDIM;
  size_t btok = (size_t)b * SS;
  __shared__ alignas(16) short QPs[64][72], Ks[64][72], Vts[64][72];
  int kblist[8];
  kblist[0] = 0; kblist[1] = NBLK - 1;
  kblist[2] = n - 1; kblist[3] = n; kblist[4] = n + 1;
#pragma unroll
  for (int r = 0; r < 3; r++)
    kblist[5 + r] = rand_attn[((size_t)h * 62 + (n - 1)) * 3 + r];
  float m[4], l[4]; acc4 O[4];
  attn_core(qbuf + (btok + (size_t)n * 64) * DD + hoff,
            kbuf + btok * DD + hoff,
            vtbuf + ((size_t)b * DD + hoff) * SS,
            kblist, 8, t, QPs, Ks, Vts, m, l, O);
#pragma unroll
  for (int r = 0; r < 4; r++) {
    float inv = 1.f / l[r];
    size_t tok = btok + (size_t)n * 64 + w * 16 + quad * 4 + r;
    short* op = ao + tok * DD + hoff;
#pragma unroll
    for (int dt = 0; dt < 4; dt++) op[dt * 16 + lc] = f2bf(O[dt][r] * inv);
  }
}

// global query blocks (0 and 63), split-K over 8 splits of 8 key-blocks each
__global__ __launch_bounds__(256) void attn_glb_mfma(
    const short* __restrict__ qbuf, const short* __restrict__ kbuf,
    const short* __restrict__ vtbuf, float* __restrict__ part) {
  int g = blockIdx.x & 1, s = blockIdx.x >> 1;  // grid.x = 16
  int h = blockIdx.y, b = blockIdx.z;
  int t = threadIdx.x, lane = t & 63, w = t >> 6, quad = lane >> 4, lc = lane & 15;
  int hoff = h * HDIM;
  size_t btok = (size_t)b * SS;
  int qblk = g ? (NBLK - 1) : 0;
  __shared__ alignas(16) short QPs[64][72], Ks[64][72], Vts[64][72];
  int kblist[8];
#pragma unroll
  for (int c = 0; c < 8; c++) kblist[c] = s * 8 + c;
  float m[4], l[4]; acc4 O[4];
  attn_core(qbuf + (btok + (size_t)qblk * 64) * DD + hoff,
            kbuf + btok * DD + hoff,
            vtbuf + ((size_t)b * DD + hoff) * SS,
            kblist, 8, t, QPs, Ks, Vts, m, l, O);
  float* pp = part + ((((size_t)b * HH + h) * 2 + g) * 8 + s) * 4224;
#pragma unroll
  for (int r = 0; r < 4; r++) {
    int row = w * 16 + quad * 4 + r;
#pragma unroll
    for (int dt = 0; dt < 4; dt++) pp[row * 64 + dt * 16 + lc] = O[dt][r];  // unnormalized
    if (lc == 0) {
      pp[4096 + row] = m[r];
      pp[4160 + row] = l[r];
    }
  }
}

__global__ __launch_bounds__(256) void attn_combine(
    const float* __restrict__ part, short* __restrict__ ao) {
  int g = blockIdx.x, h = blockIdx.y, b = blockIdx.z;
  int t = threadIdx.x, qrow = t >> 2, sub = t & 3;
  const float* base = part + (((size_t)b * HH + h) * 2 + g) * 8 * 4224;
  float mm[8], ll[8], M = -1e30f;
#pragma unroll
  for (int s = 0; s < 8; s++) {
    mm[s] = base[s * 4224 + 4096 + qrow];
    ll[s] = base[s * 4224 + 4160 + qrow];
    M = fmaxf(M, mm[s]);
  }
  float L = 0.f, O[16];
#pragma unroll
  for (int d = 0; d < 16; d++) O[d] = 0.f;
#pragma unroll
  for (int s = 0; s < 8; s++) {
    float w = __expf(mm[s] - M);
    L += w * ll[s];
    const float* Op = base + s * 4224 + qrow * 64 + sub * 16;
#pragma unroll
    for (int d = 0; d < 16; d++) O[d] += w * Op[d];
  }
  float inv = 1.f / L;
  int qblk = g ? (NBLK - 1) : 0;
  size_t tok = (size_t)b * SS + (size_t)qblk * BLKSZ + qrow;
  short* op = ao + tok * DD + h * HDIM + sub * 16;
#pragma unroll
  for (int d = 0; d < 16; d++) op[d] = f2bf(O[d] * inv);
}

// ---------- launch ----------
extern "C" void kernel_launch(void* const* d_in, const int* in_sizes, int n_in,
                              void* d_out, int out_size, void* d_ws, size_t ws_size,
                              hipStream_t stream) {
  (void)in_sizes; (void)n_in; (void)out_size; (void)ws_size;
  const float* x     = (const float*)d_in[0];
  const float* ln1_g = (const float*)d_in[1];
  const float* ln1_b = (const float*)d_in[2];
  const float* ln2_g = (const float*)d_in[3];
  const float* ln2_b = (const float*)d_in[4];
  const float* wq = (const float*)d_in[5];
  const float* bq = (const float*)d_in[6];
  const float* wk = (const float*)d_in[7];
  const float* bk = (const float*)d_in[8];
  const float* wv = (const float*)d_in[9];
  const float* bv = (const float*)d_in[10];
  const float* wo = (const float*)d_in[11];
  const float* bo = (const float*)d_in[12];
  const float* w1 = (const float*)d_in[13];
  const float* b1 = (const float*)d_in[14];
  const float* w2 = (const float*)d_in[15];
  const float* b2 = (const float*)d_in[16];
  const int* rand_attn = (const int*)d_in[17];
  float* out = (float*)d_out;

  short* wsb = (short*)d_ws;
  const size_t WD = 589824;    // 768*768
  const size_t WB = 2359296;   // 768*3072
  const size_t ACT = 6291456;  // 8192*768
  short* wqT = wsb;            // [2304][768] fused QKV^T (wq/wk/wv contiguous)
  short* wkT = wqT + WD;
  short* wvT = wkT + WD;
  short* woT = wvT + WD;
  short* w1T = woT + WD;   // [3072][768]
  short* w2T = w1T + WB;   // [768][3072]
  short* xln = w2T + WB;   // slot A
  short* qb  = xln + ACT;  // slot B  (kb, vb contiguous after -> EPI4 stride ACT)
  short* kb  = qb + ACT;   // slot C
  short* vb  = kb + ACT;   // slot D
  short* aob = vb + ACT;   // slot E
  float* partp = (float*)(aob + ACT);  // 2*12*2*8*4224 floats = 6.5 MB
  float* bqkv = partp + 3244032;       // 2304 floats
  short* vbT = xln;        // V transposed overlays slot A (xln dead after QKV GEMM)
  short* h1 = xln;         // overlays A..D (4*ACT = 8192*3072), after attention
  short* ln2b = aob;       // reuses E after out-proj consumed ao

  // 1) weight transpose+cast + bias concat, one kernel
  prep_weights<<<6921, 256, 0, stream>>>(wq, wk, wv, wo, w1, w2, bq, bk, bv, bqkv,
                                         wqT, wkT, wvT, woT, w1T, w2T);

  // 2) LN1 on x1 (= x[...,1])
  ln_kernel<<<8192, 256, 0, stream>>>(x, 2, 1, ln1_g, ln1_b, xln);

  // 3) fused QKV projection: [8192][768] @ [2304][768]^T -> q/k/v
  gemm_lds<64, 128, 4><<<dim3(18, 128), 256, 0, stream>>>(xln, wqT, bqkv, nullptr, qb, 8192, 2304, 768);

  // 3b) V -> V^T [B][D][S] for MFMA PV B-operand (overlays xln, now dead)
  transpose_bf16<<<dim3(128, 24, 2), 256, 0, stream>>>(vb, vbT);

  // 4) attention (MFMA)
  attn_mid_mfma<<<dim3(62, 12, 2), 256, 0, stream>>>(qb, kb, vbT, rand_attn, aob);
  attn_glb_mfma<<<dim3(16, 12, 2), 256, 0, stream>>>(qb, kb, vbT, partp);
  attn_combine<<<dim3(2, 12, 2), 256, 0, stream>>>(partp, aob);

  // 5) out-proj + residual(x2) -> y2 at out[...,1]   (64x64: 1536 blocks)
  gemm_lds<64, 64, 1><<<dim3(12, 128), 256, 0, stream>>>(aob, woT, bo, x, out, 8192, 768, 768);

  // 6) LN2 on y2 (strided from d_out)
  ln_kernel<<<8192, 256, 0, stream>>>((const float*)d_out, 2, 1, ln2_g, ln2_b, ln2b);

  // 7) MLP
  gemm_lds<64, 128, 2><<<dim3(24, 128), 256, 0, stream>>>(ln2b, w1T, b1, nullptr, h1, 8192, 3072, 768);
  gemm_lds<64, 64, 3><<<dim3(12, 128), 256, 0, stream>>>(h1, w2T, b2, x, out, 8192, 768, 3072);
}

// Round 6
// 470.740 us; speedup vs baseline: 1.0733x; 1.0733x over previous
//
#include <hip/hip_runtime.h>
#include <cstdint>
#include <cstddef>

// ---------- types & helpers ----------
typedef __attribute__((ext_vector_type(8))) short bfr8;   // 8 bf16 = 4 VGPRs
typedef __attribute__((ext_vector_type(4))) float acc4;   // MFMA accumulator

__device__ __forceinline__ float bf2f(short s) {
  return __uint_as_float(((unsigned)(unsigned short)s) << 16);
}
__device__ __forceinline__ short f2bf(float f) {
  unsigned u = __float_as_uint(f);
  u += 0x7fffu + ((u >> 16) & 1u);   // round-to-nearest-even
  return (short)(u >> 16);
}
// fast tanh-approx GELU: tanh via v_exp_f32, clamped to avoid inf/inf
__device__ __forceinline__ float gelu_f(float x) {
  float z = 0.7978845608028654f * (x + 0.044715f * x * x * x);
  z = fminf(fmaxf(z, -12.f), 12.f);
  float e = __expf(2.f * z);
  float th = (e - 1.f) / (e + 1.f);
  return 0.5f * x * (1.f + th);
}
// async global->LDS, 16B per lane; lds dest = wave-uniform base + lane*16
__device__ __forceinline__ void load_lds16(const short* g, short* l) {
  __builtin_amdgcn_global_load_lds(
      (const __attribute__((address_space(1))) void*)g,
      (__attribute__((address_space(3))) void*)l, 16, 0, 0);
}

// Problem constants
#define BB 2
#define SS 4096
#define DD 768
#define HH 12
#define BLKSZ 64
#define NBLK 64
#define HDIM 64

// ---------- merged weight prep: 6 transposes (fp32[K][N] -> bf16[N][K]) + bias concat ----------
__global__ __launch_bounds__(256) void prep_weights(
    const float* __restrict__ wq, const float* __restrict__ wk,
    const float* __restrict__ wv, const float* __restrict__ wo,
    const float* __restrict__ w1, const float* __restrict__ w2,
    const float* __restrict__ bq, const float* __restrict__ bk,
    const float* __restrict__ bv, float* __restrict__ bqkv,
    short* __restrict__ wqT, short* __restrict__ wkT, short* __restrict__ wvT,
    short* __restrict__ woT, short* __restrict__ w1T, short* __restrict__ w2T) {
  int id = blockIdx.x;
  if (id >= 6912) {  // bias concat, 9 blocks x 256 = 2304
    int t = (id - 6912) * 256 + threadIdx.x;
    bqkv[t] = (t < 768) ? bq[t] : (t < 1536) ? bk[t - 768] : bv[t - 1536];
    return;
  }
  const float* src; short* dst; int K, N, n0, k0;
  if (id < 2304) {
    int seg = id / 576, local = id % 576;
    K = 768; N = 768;
    n0 = (local % 24) * 32; k0 = (local / 24) * 32;
    src = seg == 0 ? wq : seg == 1 ? wk : seg == 2 ? wv : wo;
    dst = seg == 0 ? wqT : seg == 1 ? wkT : seg == 2 ? wvT : woT;
  } else if (id < 4608) {
    int local = id - 2304;
    K = 768; N = 3072;
    n0 = (local % 96) * 32; k0 = (local / 96) * 32;
    src = w1; dst = w1T;
  } else {
    int local = id - 4608;
    K = 3072; N = 768;
    n0 = (local % 24) * 32; k0 = (local / 24) * 32;
    src = w2; dst = w2T;
  }
  __shared__ float tile[32][33];
  int tx = threadIdx.x & 31, ty = threadIdx.x >> 5;  // ty in 0..7
#pragma unroll
  for (int i = 0; i < 4; i++) {
    int kk = ty + i * 8;
    tile[kk][tx] = src[(size_t)(k0 + kk) * N + n0 + tx];
  }
  __syncthreads();
#pragma unroll
  for (int i = 0; i < 4; i++) {
    int nn = ty + i * 8;
    dst[(size_t)(n0 + nn) * K + k0 + tx] = f2bf(tile[tx][nn]);
  }
}

// ---------- transpose bf16 [B][S][D] -> [B][D][S] ----------
__global__ __launch_bounds__(256) void transpose_bf16(
    const short* __restrict__ src, short* __restrict__ dst) {
  __shared__ short tile[32][33];
  int b = blockIdx.z;
  int s0 = blockIdx.x * 32, d0 = blockIdx.y * 32;
  int tx = threadIdx.x & 31, ty = threadIdx.x >> 5;  // 0..7
#pragma unroll
  for (int i = 0; i < 4; i++) {
    int ss = ty + i * 8;
    tile[ss][tx] = src[((size_t)b * SS + s0 + ss) * DD + d0 + tx];
  }
  __syncthreads();
#pragma unroll
  for (int i = 0; i < 4; i++) {
    int dd = ty + i * 8;
    dst[((size_t)b * DD + d0 + dd) * SS + s0 + tx] = tile[tx][dd];
  }
}

// ---------- LayerNorm: strided fp32 in -> contiguous bf16 out [rows][768] ----------
__global__ __launch_bounds__(256) void ln_kernel(
    const float* __restrict__ in, int stride, int off,
    const float* __restrict__ gam, const float* __restrict__ bet,
    short* __restrict__ out) {
  int row = blockIdx.x;
  int t = threadIdx.x;
  const float* base = in + (size_t)row * 768 * stride + off;
  float vals[3], s = 0.f, s2 = 0.f;
#pragma unroll
  for (int i = 0; i < 3; i++) {
    int d = t + 256 * i;
    float v = base[(size_t)d * stride];
    vals[i] = v; s += v; s2 += v * v;
  }
#pragma unroll
  for (int o = 32; o; o >>= 1) { s += __shfl_down(s, o); s2 += __shfl_down(s2, o); }
  __shared__ float red[8];
  int lane = t & 63, w = t >> 6;
  if (lane == 0) { red[w] = s; red[4 + w] = s2; }
  __syncthreads();
  s = red[0] + red[1] + red[2] + red[3];
  s2 = red[4] + red[5] + red[6] + red[7];
  float mean = s * (1.f / 768.f);
  float var = s2 * (1.f / 768.f) - mean * mean;
  float rstd = rsqrtf(var + 1e-6f);
#pragma unroll
  for (int i = 0; i < 3; i++) {
    int d = t + 256 * i;
    out[(size_t)row * 768 + d] = f2bf((vals[i] - mean) * rstd * gam[d] + bet[d]);
  }
}

// ---------- bf16 MFMA GEMM, global_load_lds staging, templated tile ----------
// Tile: BM x BN. 4 waves in 2x2; wave owns (BM/2) x (BN/2).
// C[M][N] = A[M][K] @ BT[N][K]^T + bias, epilogues:
// EPI 1: y2 = acc + bias + x[idx*2+0]  -> outf[idx*2+1]       (interleaved, RMW)
// EPI 2: out bf16 = gelu(acc + bias)
// EPI 3: y1 = acc + bias + x[idx*2+1]  -> outf[idx*2+0]       (interleaved, RMW)
// EPI 4: fused QKV: col/768 selects dest buffer (stride ACT), out bf16 row-major 768
// EPI 5: y2 = acc + bias + x[idx*2+0]  -> y2f[idx] contiguous fp32 (outp = y2f)
// EPI 6: y1 = acc + bias + x[idx*2+1]; out float2 {y1, aux[idx]} at outf[2*idx]
template <int BM, int BN, int EPI>
__global__ __launch_bounds__(256) void gemm_lds(
    const short* __restrict__ A, const short* __restrict__ BT,
    const float* __restrict__ bias, const float* __restrict__ xres,
    const float* __restrict__ aux, void* __restrict__ outp, int M, int N, int K) {
  __shared__ alignas(16) short As[BM * 64];   // unpadded: required by global_load_lds
  __shared__ alignas(16) short Bs[BN * 64];
  constexpr int TI = BM / 32;
  constexpr int TJ = BN / 32;
  int m0 = blockIdx.y * BM, n0 = blockIdx.x * BN;
  int t = threadIdx.x;
  int lane = t & 63, wave = t >> 6;
  int wm = (wave >> 1) * (BM / 2), wn = (wave & 1) * (BN / 2);
  int quad = lane >> 4, lc = lane & 15;
  acc4 acc[TI][TJ];
#pragma unroll
  for (int i = 0; i < TI; i++)
#pragma unroll
    for (int j = 0; j < TJ; j++) acc[i][j] = (acc4){0.f, 0.f, 0.f, 0.f};

  int aflat = wave * (BM * 16) + lane * 8;
  const short* Ag = A + (size_t)(m0 + (aflat >> 6)) * K + (aflat & 63);
  int bflat = wave * (BN * 16) + lane * 8;
  const short* Bg = BT + (size_t)(n0 + (bflat >> 6)) * K + (bflat & 63);

  for (int k0 = 0; k0 < K; k0 += 64) {
#pragma unroll
    for (int j = 0; j < TI; j++)
      load_lds16(Ag + k0 + (size_t)(j * 8) * K, &As[wave * (BM * 16) + j * 512]);
#pragma unroll
    for (int j = 0; j < TJ; j++)
      load_lds16(Bg + k0 + (size_t)(j * 8) * K, &Bs[wave * (BN * 16) + j * 512]);
    __syncthreads();
#pragma unroll
    for (int kk = 0; kk < 2; kk++) {
      int kof = kk * 32 + quad * 8;
      bfr8 afr[TI], bfr[TJ];
#pragma unroll
      for (int i = 0; i < TI; i++) afr[i] = *(const bfr8*)&As[(wm + i * 16 + lc) * 64 + kof];
#pragma unroll
      for (int j = 0; j < TJ; j++) bfr[j] = *(const bfr8*)&Bs[(wn + j * 16 + lc) * 64 + kof];
#pragma unroll
      for (int i = 0; i < TI; i++)
#pragma unroll
        for (int j = 0; j < TJ; j++)
          acc[i][j] = __builtin_amdgcn_mfma_f32_16x16x32_bf16(afr[i], bfr[j], acc[i][j], 0, 0, 0);
    }
    __syncthreads();
  }
  // epilogue: C/D layout col=lane&15, row=(lane>>4)*4+reg
#pragma unroll
  for (int i = 0; i < TI; i++) {
#pragma unroll
    for (int j = 0; j < TJ; j++) {
      int col = n0 + wn + j * 16 + lc;
      float bv = bias[col];
#pragma unroll
      for (int r = 0; r < 4; r++) {
        int row = m0 + wm + i * 16 + quad * 4 + r;
        float v = acc[i][j][r] + bv;
        size_t idx = (size_t)row * N + col;
        if (EPI == 1) {
          v += xres[idx * 2];
          ((float*)outp)[idx * 2 + 1] = v;
        } else if (EPI == 2) {
          ((short*)outp)[idx] = f2bf(gelu_f(v));
        } else if (EPI == 3) {
          v += xres[idx * 2 + 1];
          ((float*)outp)[idx * 2] = v;
        } else if (EPI == 4) {  // QKV split (N=2304; 16-col group never straddles 768)
          int bufidx = col / 768;
          int colm = col - bufidx * 768;
          ((short*)outp)[(size_t)bufidx * 6291456 + (size_t)row * 768 + colm] = f2bf(v);
        } else if (EPI == 5) {  // y2 contiguous fp32
          v += xres[idx * 2];
          ((float*)outp)[idx] = v;
        } else {  // EPI 6: write both halves, full-line float2
          v += xres[idx * 2 + 1];
          float2 pr; pr.x = v; pr.y = aux[idx];
          ((float2*)outp)[idx] = pr;
        }
      }
    }
  }
}

// ---------- MFMA attention core ----------
__device__ __forceinline__ void attn_core(
    const short* __restrict__ qrow0, const short* __restrict__ kbase,
    const short* __restrict__ vt_h, const int* kblist, int nch, int t,
    short (*QPs)[72], short (*Ks)[72], short (*Vts)[72],
    float* m, float* l, acc4* O) {
  int lane = t & 63, w = t >> 6, quad = lane >> 4, lc = lane & 15;
#pragma unroll
  for (int c = t; c < 512; c += 256) {
    int r = c >> 3, dc = c & 7;
    *(bfr8*)&QPs[r][dc * 8] = *(const bfr8*)&qrow0[(size_t)r * DD + dc * 8];
  }
  __syncthreads();
  bfr8 aq0 = *(const bfr8*)&QPs[w * 16 + lc][quad * 8];
  bfr8 aq1 = *(const bfr8*)&QPs[w * 16 + lc][32 + quad * 8];
#pragma unroll
  for (int r = 0; r < 4; r++) { m[r] = -1e30f; l[r] = 0.f; }
#pragma unroll
  for (int dt = 0; dt < 4; dt++) O[dt] = (acc4){0.f, 0.f, 0.f, 0.f};

  for (int ch = 0; ch < nch; ch++) {
    int kb = kblist[ch];
    __syncthreads();
#pragma unroll
    for (int c = t; c < 512; c += 256) {
      int r = c >> 3, dc = c & 7;
      *(bfr8*)&Ks[r][dc * 8] = *(const bfr8*)&kbase[((size_t)kb * 64 + r) * DD + dc * 8];
      *(bfr8*)&Vts[r][dc * 8] = *(const bfr8*)&vt_h[(size_t)r * SS + kb * 64 + dc * 8];
    }
    __syncthreads();
    acc4 sacc[4];
#pragma unroll
    for (int nt = 0; nt < 4; nt++) {
      bfr8 bk0 = *(const bfr8*)&Ks[nt * 16 + lc][quad * 8];
      bfr8 bk1 = *(const bfr8*)&Ks[nt * 16 + lc][32 + quad * 8];
      acc4 z = (acc4){0.f, 0.f, 0.f, 0.f};
      z = __builtin_amdgcn_mfma_f32_16x16x32_bf16(aq0, bk0, z, 0, 0, 0);
      z = __builtin_amdgcn_mfma_f32_16x16x32_bf16(aq1, bk1, z, 0, 0, 0);
      sacc[nt] = z;
    }
#pragma unroll
    for (int r = 0; r < 4; r++) {
      float sv[4];
#pragma unroll
      for (int nt = 0; nt < 4; nt++) sv[nt] = sacc[nt][r] * 0.125f;
      float cm = fmaxf(fmaxf(sv[0], sv[1]), fmaxf(sv[2], sv[3]));
      cm = fmaxf(cm, __shfl_xor(cm, 1));
      cm = fmaxf(cm, __shfl_xor(cm, 2));
      cm = fmaxf(cm, __shfl_xor(cm, 4));
      cm = fmaxf(cm, __shfl_xor(cm, 8));
      float mn = fmaxf(m[r], cm);
      float al = __expf(m[r] - mn);
      m[r] = mn;
      float ls = 0.f;
#pragma unroll
      for (int nt = 0; nt < 4; nt++) {
        float p = __expf(sv[nt] - mn);
        ls += p;
        QPs[w * 16 + quad * 4 + r][nt * 16 + lc] = f2bf(p);
      }
      ls += __shfl_xor(ls, 1);
      ls += __shfl_xor(ls, 2);
      ls += __shfl_xor(ls, 4);
      ls += __shfl_xor(ls, 8);
      l[r] = l[r] * al + ls;
#pragma unroll
      for (int dt = 0; dt < 4; dt++) O[dt][r] *= al;
    }
    bfr8 ap0 = *(const bfr8*)&QPs[w * 16 + lc][quad * 8];
    bfr8 ap1 = *(const bfr8*)&QPs[w * 16 + lc][32 + quad * 8];
#pragma unroll
    for (int dt = 0; dt < 4; dt++) {
      bfr8 bv0 = *(const bfr8*)&Vts[dt * 16 + lc][quad * 8];
      bfr8 bv1 = *(const bfr8*)&Vts[dt * 16 + lc][32 + quad * 8];
      O[dt] = __builtin_amdgcn_mfma_f32_16x16x32_bf16(ap0, bv0, O[dt], 0, 0, 0);
      O[dt] = __builtin_amdgcn_mfma_f32_16x16x32_bf16(ap1, bv1, O[dt], 0, 0, 0);
    }
  }
}

// middle query blocks: n = 1..62; keys = {0, 63, n-1, n, n+1, r0, r1, r2}
__global__ __launch_bounds__(256) void attn_mid_mfma(
    const short* __restrict__ qbuf, const short* __restrict__ kbuf,
    const short* __restrict__ vtbuf, const int* __restrict__ rand_attn,
    short* __restrict__ ao) {
  int n = 1 + blockIdx.x;  // 1..62
  int h = blockIdx.y, b = blockIdx.z;
  int t = threadIdx.x, lane = t & 63, w = t >> 6, quad = lane >> 4, lc = lane & 15;
  int hoff = h * HDIM;
  size_t btok = (size_t)b * SS;
  __shared__ alignas(16) short QPs[64][72], Ks[64][72], Vts[64][72];
  int kblist[8];
  kblist[0] = 0; kblist[1] = NBLK - 1;
  kblist[2] = n - 1; kblist[3] = n; kblist[4] = n + 1;
#pragma unroll
  for (int r = 0; r < 3; r++)
    kblist[5 + r] = rand_attn[((size_t)h * 62 + (n - 1)) * 3 + r];
  float m[4], l[4]; acc4 O[4];
  attn_core(qbuf + (btok + (size_t)n * 64) * DD + hoff,
            kbuf + btok * DD + hoff,
            vtbuf + ((size_t)b * DD + hoff) * SS,
            kblist, 8, t, QPs, Ks, Vts, m, l, O);
#pragma unroll
  for (int r = 0; r < 4; r++) {
    float inv = 1.f / l[r];
    size_t tok = btok + (size_t)n * 64 + w * 16 + quad * 4 + r;
    short* op = ao + tok * DD + hoff;
#pragma unroll
    for (int dt = 0; dt < 4; dt++) op[dt * 16 + lc] = f2bf(O[dt][r] * inv);
  }
}

// global query blocks (0 and 63), split-K over 8 splits of 8 key-blocks each
__global__ __launch_bounds__(256) void attn_glb_mfma(
    const short* __restrict__ qbuf, const short* __restrict__ kbuf,
    const short* __restrict__ vtbuf, float* __restrict__ part) {
  int g = blockIdx.x & 1, s = blockIdx.x >> 1;  // grid.x = 16
  int h = blockIdx.y, b = blockIdx.z;
  int t = threadIdx.x, lane = t & 63, w = t >> 6, quad = lane >> 4, lc = lane & 15;
  int hoff = h * HDIM;
  size_t btok = (size_t)b * SS;
  int qblk = g ? (NBLK - 1) : 0;
  __shared__ alignas(16) short QPs[64][72], Ks[64][72], Vts[64][72];
  int kblist[8];
#pragma unroll
  for (int c = 0; c < 8; c++) kblist[c] = s * 8 + c;
  float m[4], l[4]; acc4 O[4];
  attn_core(qbuf + (btok + (size_t)qblk * 64) * DD + hoff,
            kbuf + btok * DD + hoff,
            vtbuf + ((size_t)b * DD + hoff) * SS,
            kblist, 8, t, QPs, Ks, Vts, m, l, O);
  float* pp = part + ((((size_t)b * HH + h) * 2 + g) * 8 + s) * 4224;
#pragma unroll
  for (int r = 0; r < 4; r++) {
    int row = w * 16 + quad * 4 + r;
#pragma unroll
    for (int dt = 0; dt < 4; dt++) pp[row * 64 + dt * 16 + lc] = O[dt][r];  // unnormalized
    if (lc == 0) {
      pp[4096 + row] = m[r];
      pp[4160 + row] = l[r];
    }
  }
}

__global__ __launch_bounds__(256) void attn_combine(
    const float* __restrict__ part, short* __restrict__ ao) {
  int g = blockIdx.x, h = blockIdx.y, b = blockIdx.z;
  int t = threadIdx.x, qrow = t >> 2, sub = t & 3;
  const float* base = part + (((size_t)b * HH + h) * 2 + g) * 8 * 4224;
  float mm[8], ll[8], M = -1e30f;
#pragma unroll
  for (int s = 0; s < 8; s++) {
    mm[s] = base[s * 4224 + 4096 + qrow];
    ll[s] = base[s * 4224 + 4160 + qrow];
    M = fmaxf(M, mm[s]);
  }
  float L = 0.f, O[16];
#pragma unroll
  for (int d = 0; d < 16; d++) O[d] = 0.f;
#pragma unroll
  for (int s = 0; s < 8; s++) {
    float w = __expf(mm[s] - M);
    L += w * ll[s];
    const float* Op = base + s * 4224 + qrow * 64 + sub * 16;
#pragma unroll
    for (int d = 0; d < 16; d++) O[d] += w * Op[d];
  }
  float inv = 1.f / L;
  int qblk = g ? (NBLK - 1) : 0;
  size_t tok = (size_t)b * SS + (size_t)qblk * BLKSZ + qrow;
  short* op = ao + tok * DD + h * HDIM + sub * 16;
#pragma unroll
  for (int d = 0; d < 16; d++) op[d] = f2bf(O[d] * inv);
}

// ---------- launch ----------
extern "C" void kernel_launch(void* const* d_in, const int* in_sizes, int n_in,
                              void* d_out, int out_size, void* d_ws, size_t ws_size,
                              hipStream_t stream) {
  (void)in_sizes; (void)n_in; (void)out_size;
  const float* x     = (const float*)d_in[0];
  const float* ln1_g = (const float*)d_in[1];
  const float* ln1_b = (const float*)d_in[2];
  const float* ln2_g = (const float*)d_in[3];
  const float* ln2_b = (const float*)d_in[4];
  const float* wq = (const float*)d_in[5];
  const float* bq = (const float*)d_in[6];
  const float* wk = (const float*)d_in[7];
  const float* bk = (const float*)d_in[8];
  const float* wv = (const float*)d_in[9];
  const float* bv = (const float*)d_in[10];
  const float* wo = (const float*)d_in[11];
  const float* bo = (const float*)d_in[12];
  const float* w1 = (const float*)d_in[13];
  const float* b1 = (const float*)d_in[14];
  const float* w2 = (const float*)d_in[15];
  const float* b2 = (const float*)d_in[16];
  const int* rand_attn = (const int*)d_in[17];
  float* out = (float*)d_out;

  short* wsb = (short*)d_ws;
  const size_t WD = 589824;    // 768*768
  const size_t WB = 2359296;   // 768*3072
  const size_t ACT = 6291456;  // 8192*768
  short* wqT = wsb;            // [2304][768] fused QKV^T (wq/wk/wv contiguous)
  short* wkT = wqT + WD;
  short* wvT = wkT + WD;
  short* woT = wvT + WD;
  short* w1T = woT + WD;   // [3072][768]
  short* w2T = w1T + WB;   // [768][3072]
  short* xln = w2T + WB;   // slot A
  short* qb  = xln + ACT;  // slot B
  short* kb  = qb + ACT;   // slot C
  short* vb  = kb + ACT;   // slot D
  short* aob = vb + ACT;   // slot E
  float* partp = (float*)(aob + ACT);  // 1,622,016 floats
  float* bqkv = partp + 1622016;       // 2304 floats
  float* y2f  = bqkv + 2304;           // 8192*768 floats = 25.2 MB (new path)
  short* vbT = xln;        // V^T overlays slot A (xln dead after QKV GEMM)
  short* h1 = xln;         // overlays A..D (4*ACT), after attention
  short* ln2b = aob;       // reuses E after out-proj consumed ao

  const size_t NEED = ((size_t)(y2f + ACT) - (size_t)d_ws);  // bytes incl. y2f
  bool big = ws_size >= NEED;

  // 1) weight transpose+cast + bias concat
  prep_weights<<<6921, 256, 0, stream>>>(wq, wk, wv, wo, w1, w2, bq, bk, bv, bqkv,
                                         wqT, wkT, wvT, woT, w1T, w2T);

  // 2) LN1 on x1 (= x[...,1])
  ln_kernel<<<8192, 256, 0, stream>>>(x, 2, 1, ln1_g, ln1_b, xln);

  // 3) fused QKV projection
  gemm_lds<64, 128, 4><<<dim3(18, 128), 256, 0, stream>>>(
      xln, wqT, bqkv, nullptr, nullptr, qb, 8192, 2304, 768);

  // 3b) V -> V^T [B][D][S]
  transpose_bf16<<<dim3(128, 24, 2), 256, 0, stream>>>(vb, vbT);

  // 4) attention (MFMA)
  attn_mid_mfma<<<dim3(62, 12, 2), 256, 0, stream>>>(qb, kb, vbT, rand_attn, aob);
  attn_glb_mfma<<<dim3(16, 12, 2), 256, 0, stream>>>(qb, kb, vbT, partp);
  attn_combine<<<dim3(2, 12, 2), 256, 0, stream>>>(partp, aob);

  if (big) {
    // 5) out-proj + residual(x2) -> y2f contiguous fp32
    gemm_lds<64, 128, 5><<<dim3(6, 128), 256, 0, stream>>>(
        aob, woT, bo, x, nullptr, y2f, 8192, 768, 768);
    // 6) LN2 on y2f (contiguous)
    ln_kernel<<<8192, 256, 0, stream>>>(y2f, 1, 0, ln2_g, ln2_b, ln2b);
    // 7) MLP
    gemm_lds<64, 128, 2><<<dim3(24, 128), 256, 0, stream>>>(
        ln2b, w1T, b1, nullptr, nullptr, h1, 8192, 3072, 768);
    gemm_lds<64, 128, 6><<<dim3(6, 128), 256, 0, stream>>>(
        h1, w2T, b2, x, y2f, out, 8192, 768, 3072);
  } else {
    // fallback: R4-equivalent interleaved path
    gemm_lds<64, 128, 1><<<dim3(6, 128), 256, 0, stream>>>(
        aob, woT, bo, x, nullptr, out, 8192, 768, 768);
    ln_kernel<<<8192, 256, 0, stream>>>((const float*)d_out, 2, 1, ln2_g, ln2_b, ln2b);
    gemm_lds<64, 128, 2><<<dim3(24, 128), 256, 0, stream>>>(
        ln2b, w1T, b1, nullptr, nullptr, h1, 8192, 3072, 768);
    gemm_lds<64, 128, 3><<<dim3(6, 128), 256, 0, stream>>>(
        h1, w2T, b2, x, nullptr, out, 8192, 768, 3072);
  }
}